// Round 8
// baseline (697.337 us; speedup 1.0000x reference)
//
#include <hip/hip_runtime.h>
#include <math.h>

// GAT 3-layer, MI355X. Round 7:
// (1) attn: dwordx2 gather, 2 edges per serial iteration (halved instr/txn).
// (2) W preconverted to bf16-swizzled once (k_init); gemm stages via uint4.
// (3) tmp packed to 4B (src | ldst<<24); k_csr single-pass via LDS stage.
// (4) pool+mlp merged (k_head). 11 dispatches.

#define LRELU(x) ((x) > 0.f ? (x) : 0.2f*(x))
#define SH 8          // bucket = dst >> 8 (256 nodes per bucket)
#define TILE 4096
#define EPT 16
#define CSR_CAP 6144  // bucket stage cap (mean 4096, sigma 64 -> never hit; fallback kept)

typedef __attribute__((ext_vector_type(8))) short s16x8;
typedef __attribute__((ext_vector_type(4))) float f32x4;

__device__ inline unsigned short f2bf(float f){
  unsigned u = __float_as_uint(f);
  u += 0x7fff + ((u >> 16) & 1);   // round-to-nearest-even
  return (unsigned short)(u >> 16);
}

// ---------------- init: zero bcnt (block 0) + preconvert W1-3 (blocks 1..24)
__global__ __launch_bounds__(256) void k_init(int* __restrict__ bcnt,
    const float* __restrict__ W1, const float* __restrict__ W2, const float* __restrict__ W3,
    unsigned short* __restrict__ Wp){
  int b = blockIdx.x, t = threadIdx.x;
  if (b == 0){ bcnt[t] = 0; bcnt[256 + t] = 0; return; }
  int l = (b - 1) >> 3, part = (b - 1) & 7;
  const float* W = l == 0 ? W1 : l == 1 ? W2 : W3;
  unsigned short* Wt = Wp + l*16384;
  int id = part*256 + t;            // 0..2047 : nn = id>>4, chunk c = id&15
  int nn = id >> 4, c = id & 15;
  unsigned u[4];
  #pragma unroll
  for (int qq = 0; qq < 4; qq++){
    int k0 = 8*c + 2*qq;
    unsigned short a = f2bf(W[(size_t)k0*128 + nn]);
    unsigned short bb = f2bf(W[(size_t)(k0+1)*128 + nn]);
    u[qq] = (unsigned)a | ((unsigned)bb << 16);
  }
  int off = nn*128 + ((c ^ (nn & 15)) << 3);   // shorts, 16B aligned
  *((uint4*)(Wt + off)) = make_uint4(u[0], u[1], u[2], u[3]);
}

// ---------------- MFMA bf16 GEMM body (W pre-swizzled bf16 in global) ----
template<bool BF16IN>
__device__ __forceinline__ void gemm_body(
    unsigned short* Wt, unsigned short* Xl,
    const void* __restrict__ Xv, const unsigned short* __restrict__ Wpre,
    const float* __restrict__ attl, const float* __restrict__ attr,
    unsigned short* __restrict__ XW, float* __restrict__ AL, float* __restrict__ AR,
    int n, int bid, int gstride)
{
  int t = threadIdx.x;
  int lane = t & 63, w = t >> 6;
  int l15 = lane & 15, quad = lane >> 4;
  #pragma unroll
  for (int i = 0; i < 8; i++)
    ((uint4*)Wt)[i*256 + t] = ((const uint4*)Wpre)[i*256 + t];
  int ntiles = (n + 63) >> 6;
  int r_ = t >> 2, seg = t & 3;
  for (int tile = bid; tile < ntiles; tile += gstride){
    int row0 = tile << 6;
    __syncthreads();
    {  // stage X tile as bf16
      int grow = row0 + r_;
      unsigned short* dp = &Xl[r_*136 + seg*32];
      if (grow < n){
        if (BF16IN){
          const uint4* gp = (const uint4*)((const unsigned short*)Xv + (size_t)grow*128 + seg*32);
          #pragma unroll
          for (int i = 0; i < 4; i++) ((uint4*)dp)[i] = gp[i];
        } else {
          const float4* gp = (const float4*)((const float*)Xv + (size_t)grow*128 + seg*32);
          #pragma unroll
          for (int i = 0; i < 8; i++){
            float4 v = gp[i];
            ((unsigned*)dp)[i*2]   = (unsigned)f2bf(v.x) | ((unsigned)f2bf(v.y) << 16);
            ((unsigned*)dp)[i*2+1] = (unsigned)f2bf(v.z) | ((unsigned)f2bf(v.w) << 16);
          }
        }
      } else {
        #pragma unroll
        for (int i = 0; i < 4; i++) ((uint4*)dp)[i] = make_uint4(0,0,0,0);
      }
    }
    __syncthreads();
    f32x4 acc[4][2];
    #pragma unroll
    for (int rt = 0; rt < 4; rt++){ acc[rt][0] = (f32x4){0,0,0,0}; acc[rt][1] = (f32x4){0,0,0,0}; }
    #pragma unroll
    for (int ks = 0; ks < 4; ks++){
      s16x8 b0 = *(const s16x8*)&Wt[(w*32 + l15)*128      + (((ks*4+quad) ^ l15)<<3)];
      s16x8 b1 = *(const s16x8*)&Wt[(w*32 + 16 + l15)*128 + (((ks*4+quad) ^ l15)<<3)];
      #pragma unroll
      for (int rt = 0; rt < 4; rt++){
        s16x8 a = *(const s16x8*)&Xl[(rt*16 + l15)*136 + ks*32 + quad*8];
        acc[rt][0] = __builtin_amdgcn_mfma_f32_16x16x32_bf16(a, b0, acc[rt][0], 0, 0, 0);
        acc[rt][1] = __builtin_amdgcn_mfma_f32_16x16x32_bf16(a, b1, acc[rt][1], 0, 0, 0);
      }
    }
    __syncthreads();
    // C layout: col = l15, row = quad*4 + reg
    #pragma unroll
    for (int rt = 0; rt < 4; rt++)
      #pragma unroll
      for (int c2 = 0; c2 < 2; c2++)
        #pragma unroll
        for (int r = 0; r < 4; r++)
          Xl[(rt*16 + quad*4 + r)*136 + w*32 + c2*16 + l15] = f2bf(acc[rt][c2][r]);
    __syncthreads();
    {  // epilogue: thread -> (row r_, head seg)
      int grow = row0 + r_;
      if (grow < n){
        const unsigned short* sp = &Xl[r_*136 + seg*32];
        uint4 uu[4];
        #pragma unroll
        for (int i = 0; i < 4; i++) uu[i] = ((const uint4*)sp)[i];
        unsigned short* gx = XW + (size_t)grow*128 + seg*32;
        #pragma unroll
        for (int i = 0; i < 4; i++) ((uint4*)gx)[i] = uu[i];
        const unsigned* up = (const unsigned*)uu;
        const float4* alp = (const float4*)(attl + seg*32);
        const float4* arp = (const float4*)(attr + seg*32);
        float pl = 0.f, pr = 0.f;
        #pragma unroll
        for (int i = 0; i < 8; i++){
          unsigned ua = up[i*2], ub = up[i*2+1];
          float x0 = __uint_as_float(ua << 16);
          float x1 = __uint_as_float(ua & 0xffff0000u);
          float x2 = __uint_as_float(ub << 16);
          float x3 = __uint_as_float(ub & 0xffff0000u);
          float4 av = alp[i];
          float4 rv = arp[i];
          pl += x0*av.x + x1*av.y + x2*av.z + x3*av.w;
          pr += x0*rv.x + x1*rv.y + x2*rv.z + x3*rv.w;
        }
        AL[grow*4 + seg] = pl;
        AR[grow*4 + seg] = pr;
      }
    }
  }
}

template<bool BF16IN>
__global__ __launch_bounds__(256) void k_gemm(
    const void* __restrict__ Xv, const unsigned short* __restrict__ Wpre,
    const float* __restrict__ attl, const float* __restrict__ attr,
    unsigned short* __restrict__ XW, float* __restrict__ AL, float* __restrict__ AR, int n)
{
  __shared__ unsigned short Wt[128*128];
  __shared__ unsigned short Xl[64*136];
  gemm_body<BF16IN>(Wt, Xl, Xv, Wpre, attl, attr, XW, AL, AR, n, blockIdx.x, gridDim.x);
}

// ---------------- fused: bucket histogram (blocks < nparts) + GEMM-1 ----
__global__ __launch_bounds__(256) void k_fuse1(
    const int* __restrict__ dst, int* __restrict__ bcnt, int E, int nparts,
    const float* __restrict__ X, const unsigned short* __restrict__ Wpre,
    const float* __restrict__ attl, const float* __restrict__ attr,
    unsigned short* __restrict__ XW, float* __restrict__ AL, float* __restrict__ AR, int n)
{
  __shared__ unsigned short Wt[128*128];
  __shared__ unsigned short Xl[64*136];
  if ((int)blockIdx.x < nparts){
    int* lh = (int*)Wt;     // alias histogram onto Wt
    int t = threadIdx.x;
    for (int j = t; j < 512; j += 256) lh[j] = 0;
    __syncthreads();
    int base = blockIdx.x * TILE;
    int lim = min(base + TILE, E);
    for (int e = base + t; e < lim; e += 256)
      atomicAdd(&lh[dst[e] >> SH], 1);
    __syncthreads();
    for (int j = t; j < 512; j += 256){
      int v = lh[j];
      if (v) atomicAdd(&bcnt[j], v);
    }
    return;
  }
  gemm_body<false>(Wt, Xl, X, Wpre, attl, attr, XW, AL, AR, n,
                   (int)blockIdx.x - nparts, (int)gridDim.x - nparts);
}

// ---------------- bucket scan (block 0) + graph bounds (block 1) --------
__global__ __launch_bounds__(256) void k_bscan(const int* __restrict__ bcnt,
    int* __restrict__ bstart, int* __restrict__ bfill, int NB, int E,
    const int* __restrict__ batch, int* __restrict__ gstart, int n){
  int t = threadIdx.x;
  if (blockIdx.x == 1){
    int g = t;
    if (g > 64) return;
    int lo = 0, hi = n;
    while (lo < hi){
      int mid = (lo + hi) >> 1;
      if (batch[mid] < g) lo = mid + 1; else hi = mid;
    }
    gstart[g] = lo;
    return;
  }
  __shared__ int c[512];
  __shared__ int ps[256];
  for (int j = t; j < 512; j += 256) c[j] = (j < NB) ? bcnt[j] : 0;
  __syncthreads();
  int b0 = 2*t;
  int v0 = c[b0], v1 = c[b0+1];
  int ts = v0 + v1;
  ps[t] = ts; __syncthreads();
  for (int off = 1; off < 256; off <<= 1){
    int x = (t >= off) ? ps[t-off] : 0; __syncthreads();
    ps[t] += x; __syncthreads();
  }
  int pre = ps[t] - ts;
  if (b0   < NB){ bstart[b0]   = pre;    bfill[b0]   = pre; }
  if (b0+1 < NB){ bstart[b0+1] = pre+v0; bfill[b0+1] = pre+v0; }
  if (t == 0) bstart[NB] = E;
}

// LDS multi-split partition; tmp entries packed 4B: (ldst<<24) | src.
__global__ __launch_bounds__(256) void k_part(const int* __restrict__ src,
    const int* __restrict__ dst, int* __restrict__ bfill,
    unsigned* __restrict__ tmp, int E){
  __shared__ int2 reorder[TILE];
  __shared__ int lhist[512], lscan[512], lgbase[512];
  __shared__ int ps[256];
  int t = threadIdx.x;
  int tb = blockIdx.x * TILE;
  int tilecnt = min(TILE, E - tb);
  for (int j = t; j < 512; j += 256) lhist[j] = 0;
  __syncthreads();
  int ss[EPT], dd[EPT], rk[EPT];
  #pragma unroll
  for (int i = 0; i < EPT; i++){
    int e = tb + t + i*256;
    if (e < E){
      ss[i] = src[e]; dd[i] = dst[e];
      rk[i] = atomicAdd(&lhist[dd[i] >> SH], 1);
    }
  }
  __syncthreads();
  int b0 = 2*t;
  int v0 = lhist[b0], v1 = lhist[b0+1];
  int ts = v0 + v1;
  ps[t] = ts; __syncthreads();
  for (int off = 1; off < 256; off <<= 1){
    int x = (t >= off) ? ps[t-off] : 0; __syncthreads();
    ps[t] += x; __syncthreads();
  }
  int pre = ps[t] - ts;
  int ex0 = pre, ex1 = pre + v0;
  lscan[b0] = ex0; lscan[b0+1] = ex1;
  if (v0 > 0){ int gb = atomicAdd(&bfill[b0],   v0); lgbase[b0]   = gb - ex0; }
  if (v1 > 0){ int gb = atomicAdd(&bfill[b0+1], v1); lgbase[b0+1] = gb - ex1; }
  __syncthreads();
  #pragma unroll
  for (int i = 0; i < EPT; i++){
    int e = tb + t + i*256;
    if (e < E){
      int b = dd[i] >> SH;
      reorder[lscan[b] + rk[i]] = make_int2(ss[i], dd[i]);
    }
  }
  __syncthreads();
  for (int j = t; j < tilecnt; j += 256){
    int2 p = reorder[j];
    tmp[lgbase[p.y >> SH] + j] = (unsigned)p.x | ((unsigned)(p.y & 255) << 24);
  }
}

// One block per bucket: single global pass (LDS stage), per-node scan -> rp,
// then scatter src into the bucket's col window.
__global__ __launch_bounds__(256) void k_csr(const unsigned* __restrict__ tmp,
    const int* __restrict__ bstart, int* __restrict__ rp, int* __restrict__ col,
    int n, int E){
  __shared__ unsigned stage[CSR_CAP];
  __shared__ int lcnt[256];
  __shared__ int sc[256];
  int b = blockIdx.x, t = threadIdx.x;
  int node0 = b << SH;
  int ncnt = min(256, n - node0);
  int be = bstart[b], ee = bstart[b+1];
  int cnt = ee - be;
  lcnt[t] = 0;
  __syncthreads();
  for (int i = t; i < cnt; i += 256){
    unsigned v = tmp[be + i];
    if (i < CSR_CAP) stage[i] = v;
    atomicAdd(&lcnt[v >> 24], 1);
  }
  __syncthreads();
  int v = lcnt[t];
  sc[t] = v;
  __syncthreads();
  for (int off = 1; off < 256; off <<= 1){
    int x = (t >= off) ? sc[t-off] : 0;
    __syncthreads();
    sc[t] += x;
    __syncthreads();
  }
  int start = be + sc[t] - v;     // exclusive
  lcnt[t] = start;
  if (t < ncnt) rp[node0 + t] = start;
  if (t == 0 && node0 + ncnt == n) rp[n] = E;
  __syncthreads();
  for (int i = t; i < cnt; i += 256){
    unsigned u = (i < CSR_CAP) ? stage[i] : tmp[be + i];
    int pos = atomicAdd(&lcnt[u >> 24], 1);
    col[pos] = (int)(u & 0xFFFFFFu);
  }
}

// ---------------- Attention: one wave per dst, dwordx2, 2 edges/iter ----
template<bool BF16OUT>
__global__ __launch_bounds__(256) void k_attn(
    const unsigned short* __restrict__ XW, const float* __restrict__ AL, const float* __restrict__ AR,
    const int* __restrict__ rp, const int* __restrict__ col,
    const float* __restrict__ bias, void* __restrict__ OUT, int n)
{
  __shared__ float ebuf[4][64*4];
  __shared__ int   sbuf[4][64];
  int wv = threadIdx.x >> 6;
  int d = blockIdx.x*4 + wv;
  int lane = threadIdx.x & 63;
  if (d >= n) return;
  int start = rp[d], end = rp[d+1];
  int pair = lane >> 5, sub = lane & 31;
  int h2 = sub >> 3;                 // head of channels 4sub..4sub+3
  float4 ald4 = ((const float4*)AL)[d];
  float4 ard4 = ((const float4*)AR)[d];
  float ar0 = ard4.x, ar1 = ard4.y, ar2 = ard4.z, ar3 = ard4.w;
  float es0 = __expf(LRELU(ald4.x + ar0));
  float es1 = __expf(LRELU(ald4.y + ar1));
  float es2 = __expf(LRELU(ald4.z + ar2));
  float es3 = __expf(LRELU(ald4.w + ar3));
  float eself = h2==0?es0 : h2==1?es1 : h2==2?es2 : es3;
  const uint2* XW2 = (const uint2*)XW;   // one uint2 = 4 bf16 channels
  float acc0 = 0.f, acc1 = 0.f, acc2 = 0.f, acc3 = 0.f;
  if (pair == 0){
    uint2 xv = XW2[(unsigned)d*32 + sub];
    acc0 = eself * __uint_as_float(xv.x << 16);
    acc1 = eself * __uint_as_float(xv.x & 0xffff0000u);
    acc2 = eself * __uint_as_float(xv.y << 16);
    acc3 = eself * __uint_as_float(xv.y & 0xffff0000u);
  }
  float zl0 = 0.f, zl1 = 0.f, zl2 = 0.f, zl3 = 0.f;
  float* eb = ebuf[wv];
  int*   sb = sbuf[wv];
  for (int base = start; base < end; base += 64){
    int cnt = min(64, end - base);
    // parallel phase: lane computes exp weights for one edge (4 heads)
    int s = (lane < cnt) ? col[base + lane] : 0;
    float4 a = ((const float4*)AL)[s];
    float w0 = __expf(LRELU(a.x + ar0));
    float w1 = __expf(LRELU(a.y + ar1));
    float w2 = __expf(LRELU(a.z + ar2));
    float w3 = __expf(LRELU(a.w + ar3));
    if (lane >= cnt){ w0 = w1 = w2 = w3 = 0.f; }
    zl0 += w0; zl1 += w1; zl2 += w2; zl3 += w3;
    float4 w4; w4.x = w0; w4.y = w1; w4.z = w2; w4.w = w3;
    ((float4*)eb)[lane] = w4;
    sb[lane] = s << 5;              // premultiplied uint2 row base
    // serial gather: halves process edges j+pair; phantom edges have w=0
    #pragma unroll 4
    for (int j = 0; j < cnt; j += 2){
      int j0 = j + pair;
      float w = eb[j0*4 + h2];
      unsigned sj = (unsigned)sb[j0] + sub;
      uint2 u = XW2[sj];
      acc0 = fmaf(w, __uint_as_float(u.x << 16), acc0);
      acc1 = fmaf(w, __uint_as_float(u.x & 0xffff0000u), acc1);
      acc2 = fmaf(w, __uint_as_float(u.y << 16), acc2);
      acc3 = fmaf(w, __uint_as_float(u.y & 0xffff0000u), acc3);
    }
  }
  #pragma unroll
  for (int off = 32; off >= 1; off >>= 1){
    zl0 += __shfl_xor(zl0, off, 64);
    zl1 += __shfl_xor(zl1, off, 64);
    zl2 += __shfl_xor(zl2, off, 64);
    zl3 += __shfl_xor(zl3, off, 64);
  }
  // merge pair halves
  acc0 += __shfl_xor(acc0, 32, 64);
  acc1 += __shfl_xor(acc1, 32, 64);
  acc2 += __shfl_xor(acc2, 32, 64);
  acc3 += __shfl_xor(acc3, 32, 64);
  if (pair == 0){
    float z_h = (h2==0?zl0 : h2==1?zl1 : h2==2?zl2 : zl3) + eself;
    float rz = 1.f / z_h;
    float4 b4 = ((const float4*)bias)[sub];
    float o0 = fmaf(acc0, rz, b4.x);
    float o1 = fmaf(acc1, rz, b4.y);
    float o2 = fmaf(acc2, rz, b4.z);
    float o3 = fmaf(acc3, rz, b4.w);
    o0 = o0 > 0.f ? o0 : 0.f;
    o1 = o1 > 0.f ? o1 : 0.f;
    o2 = o2 > 0.f ? o2 : 0.f;
    o3 = o3 > 0.f ? o3 : 0.f;
    if (BF16OUT){
      uint2 pk;
      pk.x = (unsigned)f2bf(o0) | ((unsigned)f2bf(o1) << 16);
      pk.y = (unsigned)f2bf(o2) | ((unsigned)f2bf(o3) << 16);
      ((uint2*)OUT)[(unsigned)d*32 + sub] = pk;
    } else {
      float4 o; o.x = o0; o.y = o1; o.z = o2; o.w = o3;
      ((float4*)OUT)[(unsigned)d*32 + sub] = o;
    }
  }
}

// ---------------- fused mean-pool + MLP head (one block per graph) ------
__global__ __launch_bounds__(256) void k_head(const float* __restrict__ H,
    const int* __restrict__ gstart,
    const float* __restrict__ w1, const float* __restrict__ b1,
    const float* __restrict__ w2, const float* __restrict__ b2,
    float* __restrict__ out)
{
  __shared__ float p[256];
  __shared__ float gsh[128];
  __shared__ float lg[10];
  int g = blockIdx.x, t = threadIdx.x;
  int c = t & 127, half = t >> 7;
  int s0 = gstart[g], s1 = gstart[g+1];
  float sum = 0.f;
  for (int i = s0 + half; i < s1; i += 2)
    sum += H[(size_t)i*128 + c];
  p[t] = sum;
  __syncthreads();
  if (t < 128){
    float cn = fmaxf((float)(s1 - s0), 1.f);
    float pv = (p[t] + p[t + 128]) / cn;
    p[t] = pv;
  }
  __syncthreads();
  if (t < 128){
    float acc = b1[t];
    for (int k = 0; k < 128; k++) acc = fmaf(p[k], w1[k*128 + t], acc);
    gsh[t] = acc > 0.f ? acc : 0.f;
  }
  __syncthreads();
  if (t < 10){
    float a = b2[t];
    for (int k = 0; k < 128; k++) a = fmaf(gsh[k], w2[k*10 + t], a);
    lg[t] = a;
  }
  __syncthreads();
  if (t < 10){
    float mx = lg[0];
    for (int c2 = 1; c2 < 10; c2++) mx = fmaxf(mx, lg[c2]);
    float se = 0.f;
    for (int c2 = 0; c2 < 10; c2++) se += __expf(lg[c2] - mx);
    out[g*10 + t] = lg[t] - mx - logf(se);
  }
}

extern "C" void kernel_launch(void* const* d_in, const int* in_sizes, int n_in,
                              void* d_out, int out_size, void* d_ws, size_t ws_size,
                              hipStream_t stream)
{
  const float* x    = (const float*)d_in[0];
  const int* eidx   = (const int*)d_in[1];
  const int* batch  = (const int*)d_in[2];
  const float* W[3]  = {(const float*)d_in[3], (const float*)d_in[7],  (const float*)d_in[11]};
  const float* al[3] = {(const float*)d_in[4], (const float*)d_in[8],  (const float*)d_in[12]};
  const float* ar[3] = {(const float*)d_in[5], (const float*)d_in[9],  (const float*)d_in[13]};
  const float* bs[3] = {(const float*)d_in[6], (const float*)d_in[10], (const float*)d_in[14]};
  const float* l1w = (const float*)d_in[15];
  const float* l1b = (const float*)d_in[16];
  const float* l2w = (const float*)d_in[17];
  const float* l2b = (const float*)d_in[18];
  int E = in_sizes[1] / 2;
  int n = in_sizes[2];            // 100000
  const int* srcp = eidx;
  const int* dstp = eidx + E;
  int NB = (n + 255) >> SH;       // 391 buckets

  char* wsp = (char*)d_ws;
  auto alloc = [&](size_t bytes){ void* p = (void*)wsp; wsp += (bytes + 255) & ~(size_t)255; return p; };
  unsigned short* xw   = (unsigned short*)alloc((size_t)n*128*2);  // 25.6 MB bf16
  unsigned short* hbuf = (unsigned short*)alloc((size_t)n*128*2);  // 25.6 MB bf16
  float* ALb  = (float*)alloc((size_t)n*4*4);
  float* ARb  = (float*)alloc((size_t)n*4*4);
  int* rp     = (int*)alloc((size_t)(n+1)*4);
  int* col    = (int*)alloc((size_t)E*4);          // 6.4 MB
  unsigned* tmp = (unsigned*)alloc((size_t)E*4);   // 6.4 MB packed
  unsigned short* Wp = (unsigned short*)alloc(3*16384*2);  // 96 KB bf16-swizzled
  int* bcnt   = (int*)alloc(512*4);
  int* bstart = (int*)alloc(513*4);
  int* bfill  = (int*)alloc(512*4);
  int* gstart = (int*)alloc(65*4);

  float* outlog = (float*)d_out;
  float* h3     = (float*)d_out + 64*10;

  int nparts = (E + TILE - 1) / TILE;   // 391
  const int GG = 521;                   // 1563 tiles = 3 per block exactly

  k_init<<<25, 256, 0, stream>>>(bcnt, W[0], W[1], W[2], Wp);
  // fused: bucket histogram + layer-1 GEMM
  k_fuse1<<<nparts + GG, 256, 0, stream>>>(dstp, bcnt, E, nparts,
                                           x, Wp, al[0], ar[0], xw, ALb, ARb, n);
  k_bscan<<<2, 256, 0, stream>>>(bcnt, bstart, bfill, NB, E, batch, gstart, n);
  k_part <<<nparts, 256, 0, stream>>>(srcp, dstp, bfill, tmp, E);
  k_csr  <<<NB, 256, 0, stream>>>(tmp, bstart, rp, col, n, E);

  // layer 1 attention
  k_attn<true><<<(n+3)/4, 256, 0, stream>>>(xw, ALb, ARb, rp, col, bs[0], hbuf, n);
  // layer 2
  k_gemm<true><<<GG, 256, 0, stream>>>(hbuf, Wp + 16384, al[1], ar[1], xw, ALb, ARb, n);
  k_attn<true><<<(n+3)/4, 256, 0, stream>>>(xw, ALb, ARb, rp, col, bs[1], hbuf, n);
  // layer 3 -> fp32 straight into d_out
  k_gemm<true><<<GG, 256, 0, stream>>>(hbuf, Wp + 32768, al[2], ar[2], xw, ALb, ARb, n);
  k_attn<false><<<(n+3)/4, 256, 0, stream>>>(xw, ALb, ARb, rp, col, bs[2], h3, n);

  k_head<<<64, 256, 0, stream>>>(h3, gstart, l1w, l1b, l2w, l2b, outlog);
}